// Round 5
// baseline (929.018 us; speedup 1.0000x reference)
//
#include <hip/hip_runtime.h>
#include <hip/hip_bf16.h>

#define N_TOK   8192
#define DM      1024     // d_model
#define DH      16384    // d_hidden
#define KTOP    32
#define NCAND   256      // candidate buffer per row
#define DZ      0.08f    // zone half-width >= 2*delta (observed delta <= 0.031)
#define NT      16       // K-tiles of 64

typedef unsigned int uint;
typedef __attribute__((ext_vector_type(8))) short bf16x8;
typedef __attribute__((ext_vector_type(4))) float f32x4;

__device__ inline ushort f2bf(float f) {
    uint u = __float_as_uint(f);
    uint r = (u + 0x7FFFu + ((u >> 16) & 1u)) >> 16;
    return (ushort)r;
}
__device__ inline float bf2f(ushort u) {
    return __uint_as_float(((uint)u) << 16);
}

__device__ inline void load_lds16(const void* g, void* l) {
    __builtin_amdgcn_global_load_lds(
        (const __attribute__((address_space(1))) void*)g,
        (__attribute__((address_space(3))) void*)l, 16, 0, 0);
}

// ---------------------------------------------------------------------------
// Convert x -> bf16(x - b_pre)   [N_TOK, DM]
// ---------------------------------------------------------------------------
__global__ __launch_bounds__(256) void conv_x(
    const float* __restrict__ x, const float* __restrict__ b_pre,
    ushort* __restrict__ A)
{
    int i = (blockIdx.x * 256 + threadIdx.x) * 4;
    float4 v = *(const float4*)&x[i];
    float4 b = *(const float4*)&b_pre[i & (DM - 1)];
    ushort4 o;
    o.x = f2bf(v.x - b.x); o.y = f2bf(v.y - b.y);
    o.z = f2bf(v.z - b.z); o.w = f2bf(v.w - b.w);
    *(ushort4*)&A[i] = o;
}

// Convert W_enc -> bf16   [DH, DM]
__global__ __launch_bounds__(256) void conv_w(
    const float* __restrict__ W, ushort* __restrict__ B)
{
    int i = (blockIdx.x * 256 + threadIdx.x) * 4;
    float4 v = *(const float4*)&W[i];
    ushort4 o;
    o.x = f2bf(v.x); o.y = f2bf(v.y); o.z = f2bf(v.z); o.w = f2bf(v.w);
    *(ushort4*)&B[i] = o;
}

// ---------------------------------------------------------------------------
// 256x256 8-phase bf16 MFMA GEMM (T1+T2+T3+T4+T5 per m201 structure).
// pre[n][h] = A[n][:] . B[h][:] + b_act[h];  A [N_TOK,DM], B [DH,DM] bf16 NT.
// 512 thr = 8 waves (2M x 4N), per-wave 128x64 out (8x4 frags 16x16x32).
// LDS 128 KB: parity{2} x op{A,B} x kslot{2} x [256 rows][32 bf16].
// Per K-tile: 4 phases; each stages 1 half (2 x global_load_lds dwordx4,
// stage-lead 4 phases -> opposite parity), barrier+vmcnt(6) at phases 0,2
// only (counted: 3 halves stay in flight, never drains), 16 MFMA per phase
// in setprio(1). LDS reads XOR-swizzled (slot ^= (row>>1)&3); staging
// pre-swizzles the GLOBAL source so linear global_load_lds lands swizzled.
// ---------------------------------------------------------------------------
#define LDS_A(par, ks)  ((par) * 65536 + (ks) * 16384)
#define LDS_B(par, ks)  ((par) * 65536 + 32768 + (ks) * 16384)

__global__ __launch_bounds__(512, 2) void gemm8ph(
    const ushort* __restrict__ A, const ushort* __restrict__ B,
    const float* __restrict__ b_act, float* __restrict__ pre)
{
    __shared__ __align__(16) char smem[131072];

    const int tid  = threadIdx.x;
    const int wid  = tid >> 6;
    const int lane = tid & 63;
    const int wm   = wid >> 2;        // 0..1
    const int wn   = wid & 3;         // 0..3

    // XCD-aware bijective swizzle (2048 % 8 == 0): per-XCD contiguous bn range
    const int swz  = (blockIdx.x & 7) * 256 + (blockIdx.x >> 3);
    const int row0 = (swz & 31) * 256;
    const int col0 = (swz >> 5) * 256;

    f32x4 acc[8][4] = {};

    // ---- staging helper (as lambda): half = 16 KB = [256 rows][32 bf16]
    // chunk c (0..1023): row = c>>2, phys slot = c&3; logical slot =
    // (c&3) ^ ((row>>1)&3) -> read-side XOR sees linear data.
    auto stage = [&](const ushort* __restrict__ g, int grow0, int gk0,
                     int region) {
        #pragma unroll
        for (int i = 0; i < 2; ++i) {
            int c    = i * 512 + wid * 64 + lane;
            int row  = c >> 2;
            int slot = (c & 3) ^ ((row >> 1) & 3);
            load_lds16(g + (size_t)(grow0 + row) * DM + gk0 + slot * 8,
                       smem + region + (i * 512 + wid * 64) * 16);
        }
    };
    // read helpers: row-major [256][32] bf16, row stride 64 B, XOR slot swz
    auto ld_frag = [&](int region, int row) -> bf16x8 {
        int slot = (lane >> 4) ^ ((row >> 1) & 3);
        return *(const bf16x8*)(smem + region + row * 64 + slot * 16);
    };

    // prologue: stage tile 0's 4 halves in canonical order A-k0,B-k0,A-k1,B-k1
    stage(A, row0, 0,  LDS_A(0, 0));
    stage(B, col0, 0,  LDS_B(0, 0));
    stage(A, row0, 32, LDS_A(0, 1));
    stage(B, col0, 32, LDS_B(0, 1));

    for (int t = 0; t < NT; ++t) {
        const int par  = t & 1;
        const int npar = par ^ 1;
        const int tn   = (t < NT - 1) ? t + 1 : t;   // last iter: harmless dup
        const int k0n  = tn * 64;
        const int ar   = wm * 128 + (lane & 15);     // A row base (+mf*16)
        const int br   = wn * 64 + (lane & 15);      // B row base (+nf*16)

        // ---- phase 0: stage A-k0(t+1); wait(6); barrier; Q(n0,n1) x k0
        stage(A, row0, k0n, LDS_A(npar, 0));
        asm volatile("s_waitcnt vmcnt(6)" ::: "memory");
        __builtin_amdgcn_s_barrier();
        asm volatile("" ::: "memory");

        bf16x8 af[8];
        #pragma unroll
        for (int mf = 0; mf < 8; ++mf)
            af[mf] = ld_frag(LDS_A(par, 0), ar + mf * 16);
        {
            bf16x8 b0 = ld_frag(LDS_B(par, 0), br);
            bf16x8 b1 = ld_frag(LDS_B(par, 0), br + 16);
            __builtin_amdgcn_s_setprio(1);
            #pragma unroll
            for (int mf = 0; mf < 8; ++mf) {
                acc[mf][0] = __builtin_amdgcn_mfma_f32_16x16x32_bf16(af[mf], b0, acc[mf][0], 0, 0, 0);
                acc[mf][1] = __builtin_amdgcn_mfma_f32_16x16x32_bf16(af[mf], b1, acc[mf][1], 0, 0, 0);
            }
            __builtin_amdgcn_s_setprio(0);
        }

        // ---- phase 1: stage B-k0(t+1); Q(n2,n3) x k0 (af reused)
        stage(B, col0, k0n, LDS_B(npar, 0));
        {
            bf16x8 b2 = ld_frag(LDS_B(par, 0), br + 32);
            bf16x8 b3 = ld_frag(LDS_B(par, 0), br + 48);
            __builtin_amdgcn_s_setprio(1);
            #pragma unroll
            for (int mf = 0; mf < 8; ++mf) {
                acc[mf][2] = __builtin_amdgcn_mfma_f32_16x16x32_bf16(af[mf], b2, acc[mf][2], 0, 0, 0);
                acc[mf][3] = __builtin_amdgcn_mfma_f32_16x16x32_bf16(af[mf], b3, acc[mf][3], 0, 0, 0);
            }
            __builtin_amdgcn_s_setprio(0);
        }

        // ---- phase 2: stage A-k1(t+1); wait(6); barrier; Q(n0,n1) x k1
        stage(A, row0, k0n + 32, LDS_A(npar, 1));
        asm volatile("s_waitcnt vmcnt(6)" ::: "memory");
        __builtin_amdgcn_s_barrier();
        asm volatile("" ::: "memory");

        #pragma unroll
        for (int mf = 0; mf < 8; ++mf)
            af[mf] = ld_frag(LDS_A(par, 1), ar + mf * 16);
        {
            bf16x8 b0 = ld_frag(LDS_B(par, 1), br);
            bf16x8 b1 = ld_frag(LDS_B(par, 1), br + 16);
            __builtin_amdgcn_s_setprio(1);
            #pragma unroll
            for (int mf = 0; mf < 8; ++mf) {
                acc[mf][0] = __builtin_amdgcn_mfma_f32_16x16x32_bf16(af[mf], b0, acc[mf][0], 0, 0, 0);
                acc[mf][1] = __builtin_amdgcn_mfma_f32_16x16x32_bf16(af[mf], b1, acc[mf][1], 0, 0, 0);
            }
            __builtin_amdgcn_s_setprio(0);
        }

        // ---- phase 3: stage B-k1(t+1); Q(n2,n3) x k1
        stage(B, col0, k0n + 32, LDS_B(npar, 1));
        {
            bf16x8 b2 = ld_frag(LDS_B(par, 1), br + 32);
            bf16x8 b3 = ld_frag(LDS_B(par, 1), br + 48);
            __builtin_amdgcn_s_setprio(1);
            #pragma unroll
            for (int mf = 0; mf < 8; ++mf) {
                acc[mf][2] = __builtin_amdgcn_mfma_f32_16x16x32_bf16(af[mf], b2, acc[mf][2], 0, 0, 0);
                acc[mf][3] = __builtin_amdgcn_mfma_f32_16x16x32_bf16(af[mf], b3, acc[mf][3], 0, 0, 0);
            }
            __builtin_amdgcn_s_setprio(0);
        }
    }

    // epilogue: C row = (lane>>4)*4 + r, col = lane&15 (verified layout)
    float bav[4];
    #pragma unroll
    for (int nf = 0; nf < 4; ++nf)
        bav[nf] = b_act[col0 + wn * 64 + nf * 16 + (lane & 15)];
    #pragma unroll
    for (int mf = 0; mf < 8; ++mf) {
        const int grow = row0 + wm * 128 + mf * 16 + (lane >> 4) * 4;
        const int gcol = col0 + wn * 64 + (lane & 15);
        #pragma unroll
        for (int r = 0; r < 4; ++r) {
            #pragma unroll
            for (int nf = 0; nf < 4; ++nf)
                pre[(size_t)(grow + r) * DH + gcol + nf * 16] = acc[mf][nf][r] + bav[nf];
        }
    }
}

// ---------------------------------------------------------------------------
// Candidate extraction (unchanged, measured): per row, threshold bisection to
// count(>t) in [96,250], compact candidates. Also zeroes the sparse row.
// ---------------------------------------------------------------------------
__global__ __launch_bounds__(512) void topk_cand(
    const float* __restrict__ pre, float* __restrict__ sparse,
    float* __restrict__ cval, int* __restrict__ cidx, int* __restrict__ ccnt)
{
    const int row = blockIdx.x;
    const int tid = threadIdx.x;
    const float* __restrict__ p = pre + (size_t)row * DH;

    float v[32];
    #pragma unroll
    for (int j = 0; j < 32; ++j) v[j] = p[j * 512 + tid];

    float4 z = {0.f, 0.f, 0.f, 0.f};
    float4* srow = (float4*)(sparse + (size_t)row * DH);
    #pragma unroll
    for (int i = 0; i < 8; ++i) srow[tid + i * 512] = z;

    __shared__ int scount;
    float lo = -30.f, hi = 30.f, t = 0.f;
    for (int it = 0; it < 20; ++it) {
        t = 0.5f * (lo + hi);
        int c = 0;
        #pragma unroll
        for (int j = 0; j < 32; ++j) c += (v[j] > t);
        #pragma unroll
        for (int off = 32; off; off >>= 1) c += __shfl_down(c, off);
        if (tid == 0) scount = 0;
        __syncthreads();
        if ((tid & 63) == 0) atomicAdd(&scount, c);
        __syncthreads();
        int total = scount;
        __syncthreads();
        if (total >= 96 && total <= 250) break;
        if (total < 96) hi = t; else lo = t;
    }

    __shared__ int wpos;
    __shared__ float scv[NCAND];
    __shared__ int   sci[NCAND];
    if (tid == 0) wpos = 0;
    __syncthreads();
    #pragma unroll
    for (int j = 0; j < 32; ++j) {
        if (v[j] > t) {
            int pz = atomicAdd(&wpos, 1);
            if (pz < NCAND) { scv[pz] = v[j]; sci[pz] = j * 512 + tid; }
        }
    }
    __syncthreads();
    int n = min(wpos, NCAND);
    if (tid == 0) ccnt[row] = n;
    if (tid < NCAND) {
        cval[(size_t)row * NCAND + tid] = (tid < n) ? scv[tid] : -1e30f;
        cidx[(size_t)row * NCAND + tid] = (tid < n) ? sci[tid] : -1;
    }
}

// ---------------------------------------------------------------------------
// Exact top-32, sort-free (unchanged, measured-neutral and verified).
// ---------------------------------------------------------------------------
__global__ __launch_bounds__(256) void fix_topk(
    const float* __restrict__ x, const float* __restrict__ b_pre,
    const float* __restrict__ W, const float* __restrict__ b_act,
    const float* __restrict__ cval, const int* __restrict__ cidx,
    float* __restrict__ sparse, float* __restrict__ vals, int* __restrict__ inds)
{
    const int row = blockIdx.x;
    const int tid = threadIdx.x;
    const int wid = tid >> 6, lane = tid & 63;

    __shared__ float xs[DM];
    for (int i = tid; i < DM; i += 256)
        xs[i] = x[(size_t)row * DM + i] - b_pre[i];

    __shared__ float sv[NCAND];
    __shared__ float sex[NCAND];
    __shared__ int   si[NCAND];
    __shared__ int   zlist[NCAND];
    __shared__ unsigned char zf[NCAND];
    __shared__ float sa32;
    __shared__ int   scin, zn;

    const float v  = cval[(size_t)row * NCAND + tid];
    const int   id = cidx[(size_t)row * NCAND + tid];
    sv[tid] = v; si[tid] = id; sex[tid] = v;
    if (tid == 0) { scin = 0; zn = 0; }
    if (tid < KTOP) {
        vals[(size_t)row * KTOP + tid] = 0.f;
        inds[(size_t)row * KTOP + tid] = -1;
    }
    __syncthreads();

    int rank = 0;
    for (int j = 0; j < NCAND; ++j) {
        float ov = sv[j];
        rank += (ov > v) || (ov == v && si[j] < id);
    }
    if (rank == 31) sa32 = v;
    __syncthreads();

    const float a32 = sa32;
    const bool cin  = v > a32 + DZ;
    const bool zone = !cin && (v >= a32 - DZ) && (id >= 0);

    unsigned long long bal = __ballot(cin);
    if (lane == 0) atomicAdd(&scin, (int)__popcll(bal));
    if (zone) { int p = atomicAdd(&zn, 1); zlist[p] = tid; }
    zf[tid] = zone ? 1 : 0;
    __syncthreads();

    const int cin_total = scin;
    const int znum = zn;

    for (int m = wid; m < znum; m += 4) {
        int t = zlist[m];
        int h = si[t];
        const float* wrow = W + (size_t)h * DM;
        float s = 0.f;
        #pragma unroll
        for (int c = 0; c < 16; ++c)
            s = fmaf(xs[lane + c * 64], wrow[lane + c * 64], s);
        #pragma unroll
        for (int off = 32; off; off >>= 1) s += __shfl_down(s, off);
        if (lane == 0) sex[t] = s + b_act[h];
    }
    __syncthreads();

    int slot = -1;
    float outv = 0.f;
    if (cin) { slot = rank; outv = v; }
    else if (zone) {
        float ev = sex[tid];
        int zrank = 0;
        for (int j = 0; j < NCAND; ++j) {
            if (zf[j]) {
                float ov = sex[j];
                zrank += (ov > ev) || (ov == ev && si[j] < id);
            }
        }
        if (zrank < KTOP - cin_total) { slot = cin_total + zrank; outv = ev; }
    }
    if (slot >= 0) {
        float r = fmaxf(outv, 0.f);
        vals[(size_t)row * KTOP + slot] = r;
        inds[(size_t)row * KTOP + slot] = id;
        sparse[(size_t)row * DH + id] = r;
    }
}

// ---------------------------------------------------------------------------
// Transpose W_dec [DM, DH] f32 -> W_dec^T [DH, DM] bf16
// ---------------------------------------------------------------------------
__global__ __launch_bounds__(256) void transpose_dec(
    const float* __restrict__ W, ushort* __restrict__ WT)
{
    __shared__ float t[32][33];
    const int tx = threadIdx.x;
    const int ty = threadIdx.y;
    const int h0 = blockIdx.x * 32;
    const int d0 = blockIdx.y * 32;
    #pragma unroll
    for (int r = 0; r < 4; ++r)
        t[ty + r * 8][tx] = W[(size_t)(d0 + ty + r * 8) * DH + h0 + tx];
    __syncthreads();
    #pragma unroll
    for (int r = 0; r < 4; ++r)
        WT[(size_t)(h0 + ty + r * 8) * DM + d0 + tx] = f2bf(t[tx][ty + r * 8]);
}

// ---------------------------------------------------------------------------
// Decode: recon[n][d] = sum_j vals[n][j] * WdecT[inds[n][j]][d] + b_pre[d]
// ---------------------------------------------------------------------------
__global__ __launch_bounds__(256) void recon_kernel(
    const float* __restrict__ vals, const int* __restrict__ inds,
    const ushort* __restrict__ wdecT, const float* __restrict__ b_pre,
    float* __restrict__ recon)
{
    const int row = blockIdx.x;
    const int tid = threadIdx.x;
    __shared__ float lval[KTOP];
    __shared__ int   lind[KTOP];
    if (tid < KTOP) {
        lval[tid] = vals[(size_t)row * KTOP + tid];
        lind[tid] = inds[(size_t)row * KTOP + tid];
    }
    __syncthreads();

    const int d = tid * 4;
    float4 a = *(const float4*)&b_pre[d];
    #pragma unroll 8
    for (int j = 0; j < KTOP; ++j) {
        float vj = lval[j];
        int h = lind[j];
        if (vj != 0.f && h >= 0) {
            ushort4 w = *(const ushort4*)&wdecT[(size_t)h * DM + d];
            a.x = fmaf(vj, bf2f(w.x), a.x);
            a.y = fmaf(vj, bf2f(w.y), a.y);
            a.z = fmaf(vj, bf2f(w.z), a.z);
            a.w = fmaf(vj, bf2f(w.w), a.w);
        }
    }
    *(float4*)&recon[(size_t)row * DM + d] = a;
}

// ---------------------------------------------------------------------------
extern "C" void kernel_launch(void* const* d_in, const int* in_sizes, int n_in,
                              void* d_out, int out_size, void* d_ws, size_t ws_size,
                              hipStream_t stream)
{
    const float* x     = (const float*)d_in[0];
    const float* W_enc = (const float*)d_in[1];
    const float* W_dec = (const float*)d_in[2];
    const float* b_pre = (const float*)d_in[3];
    const float* b_act = (const float*)d_in[4];

    float* recon  = (float*)d_out;                       // [N, DM]
    float* sparse = recon + (size_t)N_TOK * DM;          // [N, DH]
    float* pre    = sparse + (size_t)N_TOK * DH;         // [N, DH]

    // bf16 staging of A/B inside the sparse output region (zeroed later by
    // topk_cand, which runs after gemm has consumed them)
    ushort* Abf = (ushort*)sparse;                       // 16.8 MB
    ushort* Bbf = Abf + (size_t)N_TOK * DM;              // 33.5 MB

    // workspace (~52.5 MB, proven footprint)
    float*  cval  = (float*)d_ws;                               // 8.39 MB
    int*    cidx  = (int*)(cval + (size_t)N_TOK * NCAND);       // 8.39 MB
    int*    ccnt  = cidx + (size_t)N_TOK * NCAND;               // 32 KB
    float*  vals  = (float*)(ccnt + N_TOK);                     // 1.05 MB
    int*    inds  = (int*)(vals + (size_t)N_TOK * KTOP);        // 1.05 MB
    ushort* wdecT = (ushort*)(inds + (size_t)N_TOK * KTOP);     // 33.5 MB

    conv_x<<<N_TOK * DM / 1024, 256, 0, stream>>>(x, b_pre, Abf);
    conv_w<<<DH * DM / 1024, 256, 0, stream>>>(W_enc, Bbf);

    gemm8ph<<<(N_TOK / 256) * (DH / 256), 512, 0, stream>>>(Abf, Bbf, b_act, pre);

    transpose_dec<<<dim3(DH / 32, DM / 32), dim3(32, 8), 0, stream>>>(W_dec, wdecT);

    topk_cand<<<N_TOK, 512, 0, stream>>>(pre, sparse, cval, cidx, ccnt);

    fix_topk<<<N_TOK, 256, 0, stream>>>(x, b_pre, W_enc, b_act,
                                        cval, cidx, sparse, vals, inds);

    recon_kernel<<<N_TOK, 256, 0, stream>>>(vals, inds, wdecT, b_pre, recon);
}